// Round 10
// baseline (147.734 us; speedup 1.0000x reference)
//
#include <hip/hip_runtime.h>
#include <hip/hip_bf16.h>

#define N_SEQ 4096
#define DIM   128
#define NH    4
#define DH    32
#define BATCH 4

// scale = (1/sqrt(32)) * log2(e): softmax computed in exp2 domain
#define QSCALE 0.25503495870989204f

typedef __bf16 bf16x8 __attribute__((ext_vector_type(8)));
typedef __bf16 bf16x2 __attribute__((ext_vector_type(2)));
typedef __bf16 bf16x4 __attribute__((ext_vector_type(4)));
typedef float  f32x4  __attribute__((ext_vector_type(4)));

#define MFMA(a, b, c) __builtin_amdgcn_mfma_f32_16x16x32_bf16((a), (b), (c), 0, 0, 0)

static __device__ __forceinline__ bf16x8 cvt8(const float* __restrict__ p) {
    const float4* f4 = reinterpret_cast<const float4*>(p);
    float4 a = f4[0], b = f4[1];
    bf16x8 r;
    r[0] = (__bf16)a.x; r[1] = (__bf16)a.y; r[2] = (__bf16)a.z; r[3] = (__bf16)a.w;
    r[4] = (__bf16)b.x; r[5] = (__bf16)b.y; r[6] = (__bf16)b.z; r[7] = (__bf16)b.w;
    return r;
}

static __device__ __forceinline__ f32x4 exp4(f32x4 s) {
    f32x4 r;
    r[0] = __builtin_amdgcn_exp2f(s[0]);
    r[1] = __builtin_amdgcn_exp2f(s[1]);
    r[2] = __builtin_amdgcn_exp2f(s[2]);
    r[3] = __builtin_amdgcn_exp2f(s[3]);
    return r;
}

// adjacent-pair writes -> compiler can fuse into packed bf16 converts
static __device__ __forceinline__ bf16x8 pack8(f32x4 a, f32x4 b) {
    bf16x8 o;
    o[0] = (__bf16)a[0]; o[1] = (__bf16)a[1];
    o[2] = (__bf16)a[2]; o[3] = (__bf16)a[3];
    o[4] = (__bf16)b[0]; o[5] = (__bf16)b[1];
    o[6] = (__bf16)b[2]; o[7] = (__bf16)b[3];
    return o;
}

// ---------------------------------------------------------------------------
// Kernel 1: fused QKV projection, operand-SWAPPED MFMA (A=W rows, B=x rows).
// (held control — near roofline per R7 back-solve)
// ---------------------------------------------------------------------------
__global__ __launch_bounds__(256) void proj_qkv(
    const float* __restrict__ xq, const float* __restrict__ xk, const float* __restrict__ xv,
    const float* __restrict__ Wq, const float* __restrict__ Wk, const float* __restrict__ Wv,
    const float* __restrict__ bq, const float* __restrict__ bk, const float* __restrict__ bv,
    __bf16* __restrict__ Qs, __bf16* __restrict__ Kb, __bf16* __restrict__ Vt)
{
    __shared__ __align__(16) char wlds[34816];        // 128 rows x 272 B
    const int z = blockIdx.z;
    const float* x    = (z == 0) ? xq : ((z == 1) ? xk : xv);
    const float* Wf   = (z == 0) ? Wq : ((z == 1) ? Wk : Wv);
    const float* bias = (z == 0) ? bq : ((z == 1) ? bk : bv);
    const int b    = blockIdx.y;
    const int tid  = threadIdx.x;
    const int wave = tid >> 6, lane = tid & 63;
    const int quad = lane >> 4, l15 = lane & 15;
    const int n0   = blockIdx.x * 64 + wave * 16;

    {   // stage W (fp32 -> bf16) into LDS: thread = half-row
        const int r = tid >> 1, half = tid & 1;
        const float* wsrc = Wf + r * DIM + half * 64;
        char* wdst = wlds + r * 272 + half * 128;
        #pragma unroll
        for (int i = 0; i < 8; i++)
            *(bf16x8*)(wdst + i * 16) = cvt8(wsrc + i * 8);
    }

    bf16x8 a[4];
    const float* xrow = x + (b * N_SEQ + n0 + l15) * DIM + quad * 8;
    a[0] = cvt8(xrow);      a[1] = cvt8(xrow + 32);
    a[2] = cvt8(xrow + 64); a[3] = cvt8(xrow + 96);
    __syncthreads();

    const int n = n0 + l15;                    // D col = n (swapped)
    for (int t = 0; t < 8; t++) {
        const char* wr = wlds + (t * 16 + l15) * 272 + quad * 16;
        bf16x8 w0 = *(const bf16x8*)(wr);
        bf16x8 w1 = *(const bf16x8*)(wr + 64);
        bf16x8 w2 = *(const bf16x8*)(wr + 128);
        bf16x8 w3 = *(const bf16x8*)(wr + 192);

        f32x4 acc = {0.f, 0.f, 0.f, 0.f};
        acc = MFMA(w0, a[0], acc);
        acc = MFMA(w1, a[1], acc);
        acc = MFMA(w2, a[2], acc);
        acc = MFMA(w3, a[3], acc);

        const int d0 = t * 16 + quad * 4;      // D row = d0 + r
        if (z == 0) {
            const int h = d0 >> 5, dh0 = d0 & 31;
            bf16x4 q4;
            #pragma unroll
            for (int r = 0; r < 4; r++)
                q4[r] = (__bf16)((acc[r] + bias[d0 + r]) * QSCALE);
            *(bf16x4*)(Qs + ((b * NH + h) * N_SEQ + n) * DH + dh0) = q4;
        } else if (z == 1) {
            const int h = d0 >> 5, dh0 = d0 & 31;
            bf16x4 k4;
            #pragma unroll
            for (int r = 0; r < 4; r++)
                k4[r] = (__bf16)(acc[r] + bias[d0 + r]);
            *(bf16x4*)(Kb + ((b * NH + h) * N_SEQ + n) * DH + dh0) = k4;
        } else {
            const int nl = n & 63;
            const int np = (n & ~63) | (nl & 35) | ((nl & 12) << 1) | ((nl & 16) >> 2);
            #pragma unroll
            for (int r = 0; r < 4; r++) {
                const int d = d0 + r, h = d >> 5, dh = d & 31;
                Vt[((b * NH + h) * DH + dh) * N_SEQ + np] = (__bf16)(acc[r] + bias[d]);
            }
        }
    }
}

// ---------------------------------------------------------------------------
// Kernel 2: attention — R2 structure + ONE-TILE-LAGGED PV (catalog T15,
// att[2] double-pipeline, +7-11% measured on attn).
// Mechanism: in R2, PV(t) depends on exp(t), so every 16-exp TRANS burst
// leaves the MFMA pipe with nothing independent to issue (R8's reorder
// failed because it stayed inside this chain). Now PV lags one tile:
// while tile t's S->exp runs, tile (t-1)'s 24 PV/l-MFMAs issue — fully
// independent. Tile-parity double state pfA/pfB (compile-time indices,
// rule #20); vfB_prev persists the previous superblock's tile-1 V-frags
// across the barrier in registers; kbb>0 guards the first tile; epilogue
// PV for tile 31. MFMA/exp counts and numerics unchanged.
// Spill tripwire: WRITE_SIZE must stay ~4 MB (VGPR will rise ~160-200).
// ---------------------------------------------------------------------------
__global__ __launch_bounds__(256, 2) void flash_attn(
    const __bf16* __restrict__ Qs, const __bf16* __restrict__ Kb,
    const __bf16* __restrict__ Vt, __bf16* __restrict__ ctxb)
{
    // K: 2 kh x 2 buf x 2 tiles x 5120 = 40960
    // V: 2 kh x 2 buf x 2 tiles x 4608 = 36864
    __shared__ __align__(16) char smem[77824];
    char* const Kbase = smem;                  // + kh*20480 + cur*10240 + t*5120
    char* const Vbase = smem + 40960;          // + kh*18432 + cur*9216  + t*4608

    const int bid  = blockIdx.x;
    const int bh   = bid & 15;                 // consecutive blocks cycle heads
    const int qc   = bid >> 4;                 // 0..31, 128 queries each
    const int tid  = threadIdx.x;
    const int wave = tid >> 6, lane = tid & 63;
    const int quad = lane >> 4, l15 = lane & 15;
    const int qh   = wave & 1, kh = wave >> 1; // kh in {0,1}
    const int n0   = qc * 128 + qh * 64;
    const int KH   = 2048;                     // keys per kh

    // Q B-fragments: 4 tiles of 16 queries
    const __bf16* Qp = Qs + (bh * N_SEQ + n0) * DH;
    bf16x8 qf[4];
    #pragma unroll
    for (int q = 0; q < 4; q++)
        qf[q] = *(const bf16x8*)(Qp + (q * 16 + l15) * DH + quad * 8);

    // ones A-fragment for the l-sum MFMA (l = 1*P summed over frag keys)
    bf16x8 ones;
    #pragma unroll
    for (int i = 0; i < 8; i++) ones[i] = (__bf16)1.0f;

    // staging: thread covers one 16B chunk of each tile (4 K + 4 V per superblock)
    const int r_ = tid >> 2, c_ = tid & 3;
    const __bf16* gK = Kb + (size_t)bh * N_SEQ * DH + r_ * DH + c_ * 8;
    const __bf16* gV = Vt + ((size_t)bh * DH + (tid >> 3)) * N_SEQ + (tid & 7) * 8;
    const int kofsK = r_ * 80 + c_ * 16;
    const int kofsV = (tid >> 3) * 144 + (tid & 7) * 16;

    {   // prologue: superblock 0 (2 tiles) of both kh groups -> buf 0
        #pragma unroll
        for (int g = 0; g < 2; g++) {
            #pragma unroll
            for (int t = 0; t < 2; t++) {
                bf16x8 kr = *(const bf16x8*)(gK + (size_t)(g * KH + t * 64) * DH);
                bf16x8 vr = *(const bf16x8*)(gV + g * KH + t * 64);
                *(bf16x8*)(Kbase + g * 20480 + t * 5120 + kofsK) = kr;
                *(bf16x8*)(Vbase + g * 18432 + t * 4608 + kofsV) = vr;
            }
        }
    }
    __syncthreads();

    char* const Kme = Kbase + kh * 20480;
    char* const Vme = Vbase + kh * 18432;

    f32x4 c[4][2];
    f32x4 cl[4];
    const f32x4 z4 = {0.f,0.f,0.f,0.f};
    #pragma unroll
    for (int q = 0; q < 4; q++) { c[q][0] = z4; c[q][1] = z4; cl[q] = z4; }

    // pipeline state: P of the previous tile (parity: pfA=even, pfB=odd)
    // and V-frags of the previous superblock's tile 1.
    bf16x8 pfA[4][2], pfB[4][2];
    bf16x8 vfB_prev[4];
    {
        bf16x8 zb;
        #pragma unroll
        for (int i = 0; i < 8; i++) zb[i] = (__bf16)0.0f;
        #pragma unroll
        for (int q = 0; q < 4; q++) { pfA[q][0]=zb; pfA[q][1]=zb; pfB[q][0]=zb; pfB[q][1]=zb; }
        #pragma unroll
        for (int i = 0; i < 4; i++) vfB_prev[i] = zb;
    }

    for (int kbb = 0; kbb < KH / 128; kbb++) { // 16 superblocks, 1 barrier each
        const int cur = kbb & 1;
        const char* Kc = Kme + cur * 10240;
        const char* Vc = Vme + cur * 9216;

        // prefetch next superblock for both kh groups (wraps; harmless)
        const int kn = (kbb + 1) & (KH / 128 - 1);
        bf16x8 krn[2][2], vrn[2][2];
        #pragma unroll
        for (int g = 0; g < 2; g++) {
            #pragma unroll
            for (int t = 0; t < 2; t++) {
                krn[g][t] = *(const bf16x8*)(gK + (size_t)(g * KH + kn * 128 + t * 64) * DH);
                vrn[g][t] = *(const bf16x8*)(gV + g * KH + kn * 128 + t * 64);
            }
        }

        // hoist ALL fragment ds_reads for BOTH 64-key tiles up front
        bf16x8 kfa[2][4], vfa[2][4];
        #pragma unroll
        for (int t = 0; t < 2; t++) {
            const char* Kt  = Kc + t * 5120;
            const char* Vtl = Vc + t * 4608;
            #pragma unroll
            for (int i = 0; i < 4; i++)
                kfa[t][i] = *(const bf16x8*)(Kt + (i * 16 + l15) * 80 + quad * 16);
            vfa[t][0] = *(const bf16x8*)(Vtl + l15 * 144 + quad * 16);
            vfa[t][1] = *(const bf16x8*)(Vtl + (16 + l15) * 144 + quad * 16);
            vfa[t][2] = *(const bf16x8*)(Vtl + l15 * 144 + 64 + quad * 16);
            vfa[t][3] = *(const bf16x8*)(Vtl + (16 + l15) * 144 + 64 + quad * 16);
        }

        // ---- tile 0: S+exp -> pfA ; lagged PV of prev superblock tile 1 ----
        #pragma unroll
        for (int q = 0; q < 4; q++) {
            __builtin_amdgcn_s_setprio(1);
            f32x4 sa = MFMA(kfa[0][0], qf[q], z4);
            f32x4 sb = MFMA(kfa[0][1], qf[q], z4);
            f32x4 sc = MFMA(kfa[0][2], qf[q], z4);
            f32x4 sd = MFMA(kfa[0][3], qf[q], z4);
            if (kbb > 0) {                     // independent of sa..sd
                c[q][0] = MFMA(vfB_prev[0], pfB[q][0], c[q][0]);
                c[q][1] = MFMA(vfB_prev[1], pfB[q][0], c[q][1]);
                c[q][0] = MFMA(vfB_prev[2], pfB[q][1], c[q][0]);
                c[q][1] = MFMA(vfB_prev[3], pfB[q][1], c[q][1]);
                cl[q]   = MFMA(ones, pfB[q][0], cl[q]);
                cl[q]   = MFMA(ones, pfB[q][1], cl[q]);
            }
            __builtin_amdgcn_s_setprio(0);
            f32x4 ea = exp4(sa), eb = exp4(sb), ec = exp4(sc), ed = exp4(sd);
            pfA[q][0] = pack8(ea, eb);
            pfA[q][1] = pack8(ec, ed);
        }

        // ---- tile 1: S+exp -> pfB ; lagged PV of tile 0 (pfA, vfa[0]) ------
        #pragma unroll
        for (int q = 0; q < 4; q++) {
            __builtin_amdgcn_s_setprio(1);
            f32x4 sa = MFMA(kfa[1][0], qf[q], z4);
            f32x4 sb = MFMA(kfa[1][1], qf[q], z4);
            f32x4 sc = MFMA(kfa[1][2], qf[q], z4);
            f32x4 sd = MFMA(kfa[1][3], qf[q], z4);
            c[q][0] = MFMA(vfa[0][0], pfA[q][0], c[q][0]);
            c[q][1] = MFMA(vfa[0][1], pfA[q][0], c[q][1]);
            c[q][0] = MFMA(vfa[0][2], pfA[q][1], c[q][0]);
            c[q][1] = MFMA(vfa[0][3], pfA[q][1], c[q][1]);
            cl[q]   = MFMA(ones, pfA[q][0], cl[q]);
            cl[q]   = MFMA(ones, pfA[q][1], cl[q]);
            __builtin_amdgcn_s_setprio(0);
            f32x4 ea = exp4(sa), eb = exp4(sb), ec = exp4(sc), ed = exp4(sd);
            pfB[q][0] = pack8(ea, eb);
            pfB[q][1] = pack8(ec, ed);
        }

        // carry tile-1 V-frags across the barrier in registers
        #pragma unroll
        for (int i = 0; i < 4; i++) vfB_prev[i] = vfa[1][i];

        // stage next superblock into the other buffer
        #pragma unroll
        for (int g = 0; g < 2; g++) {
            #pragma unroll
            for (int t = 0; t < 2; t++) {
                *(bf16x8*)(Kbase + g * 20480 + (cur ^ 1) * 10240 + t * 5120 + kofsK) = krn[g][t];
                *(bf16x8*)(Vbase + g * 18432 + (cur ^ 1) * 9216 + t * 4608 + kofsV) = vrn[g][t];
            }
        }
        __syncthreads();
    }

    // epilogue: PV of the final tile (tile 31 = last superblock's tile 1)
    #pragma unroll
    for (int q = 0; q < 4; q++) {
        c[q][0] = MFMA(vfB_prev[0], pfB[q][0], c[q][0]);
        c[q][1] = MFMA(vfB_prev[1], pfB[q][0], c[q][1]);
        c[q][0] = MFMA(vfB_prev[2], pfB[q][1], c[q][0]);
        c[q][1] = MFMA(vfB_prev[3], pfB[q][1], c[q][1]);
        cl[q]   = MFMA(ones, pfB[q][0], cl[q]);
        cl[q]   = MFMA(ones, pfB[q][1], cl[q]);
    }

    // split-K combine via the dead K LDS region
    if (kh == 1) {
        char* dst = smem + (qh * 64 + lane) * 144;
        #pragma unroll
        for (int q = 0; q < 4; q++) {
            *(f32x4*)(dst + (q * 2 + 0) * 16) = c[q][0];
            *(f32x4*)(dst + (q * 2 + 1) * 16) = c[q][1];
        }
        f32x4 lv = {cl[0][0], cl[1][0], cl[2][0], cl[3][0]};
        *(f32x4*)(dst + 128) = lv;
    }
    __syncthreads();
    if (kh == 0) {
        const char* src = smem + (qh * 64 + lane) * 144;
        f32x4 lp = *(const f32x4*)(src + 128);
        const int b = bh >> 2, h = bh & 3;
        #pragma unroll
        for (int q = 0; q < 4; q++) {
            c[q][0] += *(const f32x4*)(src + (q * 2 + 0) * 16);
            c[q][1] += *(const f32x4*)(src + (q * 2 + 1) * 16);
            const float inv = 1.0f / (cl[q][0] + lp[q]);
            const int qg = n0 + q * 16 + l15;
            __bf16* dst = ctxb + ((size_t)(b * N_SEQ + qg)) * DIM + h * DH + quad * 4;
            #pragma unroll
            for (int dt = 0; dt < 2; dt++) {
                f32x4 cc = c[q][dt];
                bf16x2 e0 = {(__bf16)(cc[0] * inv), (__bf16)(cc[1] * inv)};
                bf16x2 e1 = {(__bf16)(cc[2] * inv), (__bf16)(cc[3] * inv)};
                *(bf16x2*)(dst + dt * 16)     = e0;
                *(bf16x2*)(dst + dt * 16 + 2) = e1;
            }
        }
    }
}

// ---------------------------------------------------------------------------
// Kernel 3: output projection, operand-swapped + Wo staged in LDS.
// (held control — near roofline per R7 back-solve)
// ---------------------------------------------------------------------------
__global__ __launch_bounds__(256) void out_proj(
    const __bf16* __restrict__ ctxb, const float* __restrict__ Wo,
    const float* __restrict__ bo, float* __restrict__ out)
{
    __shared__ __align__(16) char wlds[34816];
    const int b    = blockIdx.y;
    const int tid  = threadIdx.x;
    const int wave = tid >> 6, lane = tid & 63;
    const int quad = lane >> 4, l15 = lane & 15;
    const int n0   = blockIdx.x * 64 + wave * 16;

    {   // stage Wo (fp32 -> bf16) into LDS
        const int r = tid >> 1, half = tid & 1;
        const float* wsrc = Wo + r * DIM + half * 64;
        char* wdst = wlds + r * 272 + half * 128;
        #pragma unroll
        for (int i = 0; i < 8; i++)
            *(bf16x8*)(wdst + i * 16) = cvt8(wsrc + i * 8);
    }

    bf16x8 a[4];
    const __bf16* crow = ctxb + (b * N_SEQ + n0 + l15) * DIM + quad * 8;
    a[0] = *(const bf16x8*)(crow);
    a[1] = *(const bf16x8*)(crow + 32);
    a[2] = *(const bf16x8*)(crow + 64);
    a[3] = *(const bf16x8*)(crow + 96);
    __syncthreads();

    const int n = n0 + l15;
    for (int t = 0; t < 8; t++) {
        const char* wr = wlds + (t * 16 + l15) * 272 + quad * 16;
        bf16x8 w0 = *(const bf16x8*)(wr);
        bf16x8 w1 = *(const bf16x8*)(wr + 64);
        bf16x8 w2 = *(const bf16x8*)(wr + 128);
        bf16x8 w3 = *(const bf16x8*)(wr + 192);

        f32x4 acc = {0.f, 0.f, 0.f, 0.f};
        acc = MFMA(w0, a[0], acc);
        acc = MFMA(w1, a[1], acc);
        acc = MFMA(w2, a[2], acc);
        acc = MFMA(w3, a[3], acc);

        const int d0 = t * 16 + quad * 4;
        float4 o;
        o.x = acc[0] + bo[d0];
        o.y = acc[1] + bo[d0 + 1];
        o.z = acc[2] + bo[d0 + 2];
        o.w = acc[3] + bo[d0 + 3];
        *(float4*)(out + (b * N_SEQ + n) * DIM + d0) = o;
    }
}

// ---------------------------------------------------------------------------
extern "C" void kernel_launch(void* const* d_in, const int* in_sizes, int n_in,
                              void* d_out, int out_size, void* d_ws, size_t ws_size,
                              hipStream_t stream)
{
    const float* query = (const float*)d_in[0];
    const float* key   = (const float*)d_in[1];
    const float* value = (const float*)d_in[2];
    const float* Wq = (const float*)d_in[3];
    const float* bq = (const float*)d_in[4];
    const float* Wk = (const float*)d_in[5];
    const float* bk = (const float*)d_in[6];
    const float* Wv = (const float*)d_in[7];
    const float* bv = (const float*)d_in[8];
    const float* Wo = (const float*)d_in[9];
    const float* bo = (const float*)d_in[10];
    float* out = (float*)d_out;

    char* ws = (char*)d_ws;
    const size_t e = (size_t)BATCH * N_SEQ * DIM;   // 2,097,152 elements
    __bf16* Qs   = (__bf16*)(ws);                   // 4 MB  [B,H,N,32] scaled
    __bf16* Kb   = (__bf16*)(ws + 2 * e);           // 4 MB  [B,H,N,32] identity
    __bf16* Vt   = (__bf16*)(ws + 4 * e);           // 4 MB  [B,H,32,N] key-permuted
    __bf16* ctxb = (__bf16*)(ws + 6 * e);           // 4 MB  [B,N,128]

    proj_qkv<<<dim3(64, BATCH, 3), 256, 0, stream>>>(
        query, key, value, Wq, Wk, Wv, bq, bk, bv, Qs, Kb, Vt);
    flash_attn<<<dim3(512), 256, 0, stream>>>(Qs, Kb, Vt, ctxb);
    out_proj<<<dim3(64, BATCH), 256, 0, stream>>>(ctxb, Wo, bo, out);
}

// Round 11
// 147.057 us; speedup vs baseline: 1.0046x; 1.0046x over previous
//
#include <hip/hip_runtime.h>
#include <hip/hip_bf16.h>

#define N_SEQ 4096
#define DIM   128
#define NH    4
#define DH    32
#define BATCH 4

// scale = (1/sqrt(32)) * log2(e): softmax computed in exp2 domain
#define QSCALE 0.25503495870989204f

typedef __bf16 bf16x8 __attribute__((ext_vector_type(8)));
typedef __bf16 bf16x2 __attribute__((ext_vector_type(2)));
typedef __bf16 bf16x4 __attribute__((ext_vector_type(4)));
typedef float  f32x4  __attribute__((ext_vector_type(4)));

#define MFMA(a, b, c) __builtin_amdgcn_mfma_f32_16x16x32_bf16((a), (b), (c), 0, 0, 0)

static __device__ __forceinline__ bf16x8 cvt8(const float* __restrict__ p) {
    const float4* f4 = reinterpret_cast<const float4*>(p);
    float4 a = f4[0], b = f4[1];
    bf16x8 r;
    r[0] = (__bf16)a.x; r[1] = (__bf16)a.y; r[2] = (__bf16)a.z; r[3] = (__bf16)a.w;
    r[4] = (__bf16)b.x; r[5] = (__bf16)b.y; r[6] = (__bf16)b.z; r[7] = (__bf16)b.w;
    return r;
}

static __device__ __forceinline__ f32x4 exp4(f32x4 s) {
    f32x4 r;
    r[0] = __builtin_amdgcn_exp2f(s[0]);
    r[1] = __builtin_amdgcn_exp2f(s[1]);
    r[2] = __builtin_amdgcn_exp2f(s[2]);
    r[3] = __builtin_amdgcn_exp2f(s[3]);
    return r;
}

// adjacent-pair writes -> compiler can fuse into packed bf16 converts
static __device__ __forceinline__ bf16x8 pack8(f32x4 a, f32x4 b) {
    bf16x8 o;
    o[0] = (__bf16)a[0]; o[1] = (__bf16)a[1];
    o[2] = (__bf16)a[2]; o[3] = (__bf16)a[3];
    o[4] = (__bf16)b[0]; o[5] = (__bf16)b[1];
    o[6] = (__bf16)b[2]; o[7] = (__bf16)b[3];
    return o;
}

// ---------------------------------------------------------------------------
// Kernel 1: fused QKV projection, operand-SWAPPED MFMA (A=W rows, B=x rows).
// (held control — near roofline per R7 back-solve: proj+out ~13us combined)
// ---------------------------------------------------------------------------
__global__ __launch_bounds__(256) void proj_qkv(
    const float* __restrict__ xq, const float* __restrict__ xk, const float* __restrict__ xv,
    const float* __restrict__ Wq, const float* __restrict__ Wk, const float* __restrict__ Wv,
    const float* __restrict__ bq, const float* __restrict__ bk, const float* __restrict__ bv,
    __bf16* __restrict__ Qs, __bf16* __restrict__ Kb, __bf16* __restrict__ Vt)
{
    __shared__ __align__(16) char wlds[34816];        // 128 rows x 272 B
    const int z = blockIdx.z;
    const float* x    = (z == 0) ? xq : ((z == 1) ? xk : xv);
    const float* Wf   = (z == 0) ? Wq : ((z == 1) ? Wk : Wv);
    const float* bias = (z == 0) ? bq : ((z == 1) ? bk : bv);
    const int b    = blockIdx.y;
    const int tid  = threadIdx.x;
    const int wave = tid >> 6, lane = tid & 63;
    const int quad = lane >> 4, l15 = lane & 15;
    const int n0   = blockIdx.x * 64 + wave * 16;

    {   // stage W (fp32 -> bf16) into LDS: thread = half-row
        const int r = tid >> 1, half = tid & 1;
        const float* wsrc = Wf + r * DIM + half * 64;
        char* wdst = wlds + r * 272 + half * 128;
        #pragma unroll
        for (int i = 0; i < 8; i++)
            *(bf16x8*)(wdst + i * 16) = cvt8(wsrc + i * 8);
    }

    bf16x8 a[4];
    const float* xrow = x + (b * N_SEQ + n0 + l15) * DIM + quad * 8;
    a[0] = cvt8(xrow);      a[1] = cvt8(xrow + 32);
    a[2] = cvt8(xrow + 64); a[3] = cvt8(xrow + 96);
    __syncthreads();

    const int n = n0 + l15;                    // D col = n (swapped)
    for (int t = 0; t < 8; t++) {
        const char* wr = wlds + (t * 16 + l15) * 272 + quad * 16;
        bf16x8 w0 = *(const bf16x8*)(wr);
        bf16x8 w1 = *(const bf16x8*)(wr + 64);
        bf16x8 w2 = *(const bf16x8*)(wr + 128);
        bf16x8 w3 = *(const bf16x8*)(wr + 192);

        f32x4 acc = {0.f, 0.f, 0.f, 0.f};
        acc = MFMA(w0, a[0], acc);
        acc = MFMA(w1, a[1], acc);
        acc = MFMA(w2, a[2], acc);
        acc = MFMA(w3, a[3], acc);

        const int d0 = t * 16 + quad * 4;      // D row = d0 + r
        if (z == 0) {
            const int h = d0 >> 5, dh0 = d0 & 31;
            bf16x4 q4;
            #pragma unroll
            for (int r = 0; r < 4; r++)
                q4[r] = (__bf16)((acc[r] + bias[d0 + r]) * QSCALE);
            *(bf16x4*)(Qs + ((b * NH + h) * N_SEQ + n) * DH + dh0) = q4;
        } else if (z == 1) {
            const int h = d0 >> 5, dh0 = d0 & 31;
            bf16x4 k4;
            #pragma unroll
            for (int r = 0; r < 4; r++)
                k4[r] = (__bf16)(acc[r] + bias[d0 + r]);
            *(bf16x4*)(Kb + ((b * NH + h) * N_SEQ + n) * DH + dh0) = k4;
        } else {
            const int nl = n & 63;
            const int np = (n & ~63) | (nl & 35) | ((nl & 12) << 1) | ((nl & 16) >> 2);
            #pragma unroll
            for (int r = 0; r < 4; r++) {
                const int d = d0 + r, h = d >> 5, dh = d & 31;
                Vt[((b * NH + h) * DH + dh) * N_SEQ + np] = (__bf16)(acc[r] + bias[d]);
            }
        }
    }
}

// ---------------------------------------------------------------------------
// Kernel 2: attention — FINAL: exact R2 body (best measured: 50.4-51.6 us
// across three independent benches). Session-verified conclusions:
//  - 2 waves/SIMD + 64 q/wave + 128-key superblock is the balance point of
//    {TRANS ~27%, MFMA ~32%, VALU ~42%, LDS ~40%} with the serial
//    ds_read->S-MFMA->exp->pack->PV chain. Perturbations all regressed:
//    32q/4-waves-SIMD (R1 63us, R5 53.7us — LDS traffic doubles),
//    L2-direct (R3 58.9us — latency exposure at 2 waves),
//    launch_bounds(,4) @64q (R4 — unified-RF spill, 650MB scratch),
//    explicit phase reorder (R8 52.9us), lagged PV / T15 (R10 53.6us) —
//    hipcc's own schedule of this loop beats every hand reorder.
//  - Verified wins kept: l-sum via ones-MFMA (kills 2048 VALU adds +
//    post-loop shuffle reduce), setprio around MFMA clusters, both-tile
//    fragment hoist, 1 barrier/superblock, exp2-domain softmax (QSCALE
//    folded at proj), key-permuted Vt so P packs straight into PV A-frags.
//  - Next structural level (not attempted): 8-wave 32x32-MFMA swapped-QK^T
//    in-register-softmax rewrite (guide SB ladder, ~2x attn ceiling).
// ---------------------------------------------------------------------------
__global__ __launch_bounds__(256, 2) void flash_attn(
    const __bf16* __restrict__ Qs, const __bf16* __restrict__ Kb,
    const __bf16* __restrict__ Vt, __bf16* __restrict__ ctxb)
{
    // K: 2 kh x 2 buf x 2 tiles x 5120 = 40960
    // V: 2 kh x 2 buf x 2 tiles x 4608 = 36864
    __shared__ __align__(16) char smem[77824];
    char* const Kbase = smem;                  // + kh*20480 + cur*10240 + t*5120
    char* const Vbase = smem + 40960;          // + kh*18432 + cur*9216  + t*4608

    const int bid  = blockIdx.x;
    const int bh   = bid & 15;                 // consecutive blocks cycle heads
    const int qc   = bid >> 4;                 // 0..31, 128 queries each
    const int tid  = threadIdx.x;
    const int wave = tid >> 6, lane = tid & 63;
    const int quad = lane >> 4, l15 = lane & 15;
    const int qh   = wave & 1, kh = wave >> 1; // kh in {0,1}
    const int n0   = qc * 128 + qh * 64;
    const int KH   = 2048;                     // keys per kh

    // Q B-fragments: 4 tiles of 16 queries
    const __bf16* Qp = Qs + (bh * N_SEQ + n0) * DH;
    bf16x8 qf[4];
    #pragma unroll
    for (int q = 0; q < 4; q++)
        qf[q] = *(const bf16x8*)(Qp + (q * 16 + l15) * DH + quad * 8);

    // ones A-fragment for the l-sum MFMA (l = 1*P summed over frag keys)
    bf16x8 ones;
    #pragma unroll
    for (int i = 0; i < 8; i++) ones[i] = (__bf16)1.0f;

    // staging: thread covers one 16B chunk of each tile (4 K + 4 V per superblock)
    const int r_ = tid >> 2, c_ = tid & 3;
    const __bf16* gK = Kb + (size_t)bh * N_SEQ * DH + r_ * DH + c_ * 8;
    const __bf16* gV = Vt + ((size_t)bh * DH + (tid >> 3)) * N_SEQ + (tid & 7) * 8;
    const int kofsK = r_ * 80 + c_ * 16;
    const int kofsV = (tid >> 3) * 144 + (tid & 7) * 16;

    {   // prologue: superblock 0 (2 tiles) of both kh groups -> buf 0
        #pragma unroll
        for (int g = 0; g < 2; g++) {
            #pragma unroll
            for (int t = 0; t < 2; t++) {
                bf16x8 kr = *(const bf16x8*)(gK + (size_t)(g * KH + t * 64) * DH);
                bf16x8 vr = *(const bf16x8*)(gV + g * KH + t * 64);
                *(bf16x8*)(Kbase + g * 20480 + t * 5120 + kofsK) = kr;
                *(bf16x8*)(Vbase + g * 18432 + t * 4608 + kofsV) = vr;
            }
        }
    }
    __syncthreads();

    char* const Kme = Kbase + kh * 20480;
    char* const Vme = Vbase + kh * 18432;

    f32x4 c[4][2];
    f32x4 cl[4];
    const f32x4 z4 = {0.f,0.f,0.f,0.f};
    #pragma unroll
    for (int q = 0; q < 4; q++) { c[q][0] = z4; c[q][1] = z4; cl[q] = z4; }

    for (int kbb = 0; kbb < KH / 128; kbb++) { // 16 superblocks, 1 barrier each
        const int cur = kbb & 1;
        const char* Kc = Kme + cur * 10240;
        const char* Vc = Vme + cur * 9216;

        // prefetch next superblock for both kh groups (wraps; harmless)
        const int kn = (kbb + 1) & (KH / 128 - 1);
        bf16x8 krn[2][2], vrn[2][2];
        #pragma unroll
        for (int g = 0; g < 2; g++) {
            #pragma unroll
            for (int t = 0; t < 2; t++) {
                krn[g][t] = *(const bf16x8*)(gK + (size_t)(g * KH + kn * 128 + t * 64) * DH);
                vrn[g][t] = *(const bf16x8*)(gV + g * KH + kn * 128 + t * 64);
            }
        }

        // hoist ALL fragment ds_reads for BOTH 64-key tiles up front:
        // tile1's LDS latency hides under tile0's full compute chain.
        bf16x8 kfa[2][4], vfa[2][4];
        #pragma unroll
        for (int t = 0; t < 2; t++) {
            const char* Kt  = Kc + t * 5120;
            const char* Vtl = Vc + t * 4608;
            #pragma unroll
            for (int i = 0; i < 4; i++)
                kfa[t][i] = *(const bf16x8*)(Kt + (i * 16 + l15) * 80 + quad * 16);
            vfa[t][0] = *(const bf16x8*)(Vtl + l15 * 144 + quad * 16);
            vfa[t][1] = *(const bf16x8*)(Vtl + (16 + l15) * 144 + quad * 16);
            vfa[t][2] = *(const bf16x8*)(Vtl + l15 * 144 + 64 + quad * 16);
            vfa[t][3] = *(const bf16x8*)(Vtl + (16 + l15) * 144 + 64 + quad * 16);
        }

        #pragma unroll
        for (int t = 0; t < 2; t++) {          // two 64-key tiles, no barrier between
            // scores + P (in registers) per query tile
            bf16x8 pf[4][2];
            #pragma unroll
            for (int q = 0; q < 4; q++) {
                __builtin_amdgcn_s_setprio(1);
                f32x4 sa = MFMA(kfa[t][0], qf[q], z4);
                f32x4 sb = MFMA(kfa[t][1], qf[q], z4);
                f32x4 sc = MFMA(kfa[t][2], qf[q], z4);
                f32x4 sd = MFMA(kfa[t][3], qf[q], z4);
                __builtin_amdgcn_s_setprio(0);
                f32x4 ea = exp4(sa), eb = exp4(sb), ec = exp4(sc), ed = exp4(sd);
                pf[q][0] = pack8(ea, eb);      // keys g0
                pf[q][1] = pack8(ec, ed);      // keys g1
            }

            __builtin_amdgcn_s_setprio(1);
            #pragma unroll
            for (int q = 0; q < 4; q++) {
                c[q][0] = MFMA(vfa[t][0], pf[q][0], c[q][0]);
                c[q][1] = MFMA(vfa[t][1], pf[q][0], c[q][1]);
                c[q][0] = MFMA(vfa[t][2], pf[q][1], c[q][0]);
                c[q][1] = MFMA(vfa[t][3], pf[q][1], c[q][1]);
                cl[q]   = MFMA(ones, pf[q][0], cl[q]);   // l-sum on MFMA pipe
                cl[q]   = MFMA(ones, pf[q][1], cl[q]);
            }
            __builtin_amdgcn_s_setprio(0);
        }

        // stage next superblock into the other buffer
        #pragma unroll
        for (int g = 0; g < 2; g++) {
            #pragma unroll
            for (int t = 0; t < 2; t++) {
                *(bf16x8*)(Kbase + g * 20480 + (cur ^ 1) * 10240 + t * 5120 + kofsK) = krn[g][t];
                *(bf16x8*)(Vbase + g * 18432 + (cur ^ 1) * 9216 + t * 4608 + kofsV) = vrn[g][t];
            }
        }
        __syncthreads();
    }

    // split-K combine via the dead K LDS region
    if (kh == 1) {
        char* dst = smem + (qh * 64 + lane) * 144;
        #pragma unroll
        for (int q = 0; q < 4; q++) {
            *(f32x4*)(dst + (q * 2 + 0) * 16) = c[q][0];
            *(f32x4*)(dst + (q * 2 + 1) * 16) = c[q][1];
        }
        f32x4 lv = {cl[0][0], cl[1][0], cl[2][0], cl[3][0]};
        *(f32x4*)(dst + 128) = lv;
    }
    __syncthreads();
    if (kh == 0) {
        const char* src = smem + (qh * 64 + lane) * 144;
        f32x4 lp = *(const f32x4*)(src + 128);
        const int b = bh >> 2, h = bh & 3;
        #pragma unroll
        for (int q = 0; q < 4; q++) {
            c[q][0] += *(const f32x4*)(src + (q * 2 + 0) * 16);
            c[q][1] += *(const f32x4*)(src + (q * 2 + 1) * 16);
            const float inv = 1.0f / (cl[q][0] + lp[q]);
            const int qg = n0 + q * 16 + l15;
            __bf16* dst = ctxb + ((size_t)(b * N_SEQ + qg)) * DIM + h * DH + quad * 4;
            #pragma unroll
            for (int dt = 0; dt < 2; dt++) {
                f32x4 cc = c[q][dt];
                bf16x2 e0 = {(__bf16)(cc[0] * inv), (__bf16)(cc[1] * inv)};
                bf16x2 e1 = {(__bf16)(cc[2] * inv), (__bf16)(cc[3] * inv)};
                *(bf16x2*)(dst + dt * 16)     = e0;
                *(bf16x2*)(dst + dt * 16 + 2) = e1;
            }
        }
    }
}

// ---------------------------------------------------------------------------
// Kernel 3: output projection, operand-swapped + Wo staged in LDS.
// (held control — near roofline per R7 back-solve)
// ---------------------------------------------------------------------------
__global__ __launch_bounds__(256) void out_proj(
    const __bf16* __restrict__ ctxb, const float* __restrict__ Wo,
    const float* __restrict__ bo, float* __restrict__ out)
{
    __shared__ __align__(16) char wlds[34816];
    const int b    = blockIdx.y;
    const int tid  = threadIdx.x;
    const int wave = tid >> 6, lane = tid & 63;
    const int quad = lane >> 4, l15 = lane & 15;
    const int n0   = blockIdx.x * 64 + wave * 16;

    {   // stage Wo (fp32 -> bf16) into LDS
        const int r = tid >> 1, half = tid & 1;
        const float* wsrc = Wo + r * DIM + half * 64;
        char* wdst = wlds + r * 272 + half * 128;
        #pragma unroll
        for (int i = 0; i < 8; i++)
            *(bf16x8*)(wdst + i * 16) = cvt8(wsrc + i * 8);
    }

    bf16x8 a[4];
    const __bf16* crow = ctxb + (b * N_SEQ + n0 + l15) * DIM + quad * 8;
    a[0] = *(const bf16x8*)(crow);
    a[1] = *(const bf16x8*)(crow + 32);
    a[2] = *(const bf16x8*)(crow + 64);
    a[3] = *(const bf16x8*)(crow + 96);
    __syncthreads();

    const int n = n0 + l15;
    for (int t = 0; t < 8; t++) {
        const char* wr = wlds + (t * 16 + l15) * 272 + quad * 16;
        bf16x8 w0 = *(const bf16x8*)(wr);
        bf16x8 w1 = *(const bf16x8*)(wr + 64);
        bf16x8 w2 = *(const bf16x8*)(wr + 128);
        bf16x8 w3 = *(const bf16x8*)(wr + 192);

        f32x4 acc = {0.f, 0.f, 0.f, 0.f};
        acc = MFMA(w0, a[0], acc);
        acc = MFMA(w1, a[1], acc);
        acc = MFMA(w2, a[2], acc);
        acc = MFMA(w3, a[3], acc);

        const int d0 = t * 16 + quad * 4;
        float4 o;
        o.x = acc[0] + bo[d0];
        o.y = acc[1] + bo[d0 + 1];
        o.z = acc[2] + bo[d0 + 2];
        o.w = acc[3] + bo[d0 + 3];
        *(float4*)(out + (b * N_SEQ + n) * DIM + d0) = o;
    }
}

// ---------------------------------------------------------------------------
extern "C" void kernel_launch(void* const* d_in, const int* in_sizes, int n_in,
                              void* d_out, int out_size, void* d_ws, size_t ws_size,
                              hipStream_t stream)
{
    const float* query = (const float*)d_in[0];
    const float* key   = (const float*)d_in[1];
    const float* value = (const float*)d_in[2];
    const float* Wq = (const float*)d_in[3];
    const float* bq = (const float*)d_in[4];
    const float* Wk = (const float*)d_in[5];
    const float* bk = (const float*)d_in[6];
    const float* Wv = (const float*)d_in[7];
    const float* bv = (const float*)d_in[8];
    const float* Wo = (const float*)d_in[9];
    const float* bo = (const float*)d_in[10];
    float* out = (float*)d_out;

    char* ws = (char*)d_ws;
    const size_t e = (size_t)BATCH * N_SEQ * DIM;   // 2,097,152 elements
    __bf16* Qs   = (__bf16*)(ws);                   // 4 MB  [B,H,N,32] scaled
    __bf16* Kb   = (__bf16*)(ws + 2 * e);           // 4 MB  [B,H,N,32] identity
    __bf16* Vt   = (__bf16*)(ws + 4 * e);           // 4 MB  [B,H,32,N] key-permuted
    __bf16* ctxb = (__bf16*)(ws + 6 * e);           // 4 MB  [B,N,128]

    proj_qkv<<<dim3(64, BATCH, 3), 256, 0, stream>>>(
        query, key, value, Wq, Wk, Wv, bq, bk, bv, Qs, Kb, Vt);
    flash_attn<<<dim3(512), 256, 0, stream>>>(Qs, Kb, Vt, ctxb);
    out_proj<<<dim3(64, BATCH), 256, 0, stream>>>(ctxb, Wo, bo, out);
}